// Round 17
// baseline (307.374 us; speedup 1.0000x reference)
//
#include <hip/hip_runtime.h>

#define NH 16
#define DM 1024
#define SQ 2048
#define BT 4

typedef __attribute__((ext_vector_type(8))) short bf16x8;
typedef __attribute__((ext_vector_type(4))) short sh4;
typedef __attribute__((ext_vector_type(4))) float f4;
typedef __attribute__((ext_vector_type(4))) float fv4;
typedef __attribute__((ext_vector_type(4))) unsigned uv4;
typedef unsigned short u16;

#define M2BIAS 23.083120654f   /* 16 * log2(e) */
#define SCALE2 0.18033688f     /* (1/8) * log2(e) */

__device__ __forceinline__ u16 f2bf(float f) {
    union { float f; unsigned u; } v; v.f = f;
    unsigned r = v.u + 0x7FFFu + ((v.u >> 16) & 1u);
    return (u16)(r >> 16);
}

__device__ __forceinline__ float fast_exp2(float x) {
#if __has_builtin(__builtin_amdgcn_exp2f)
    return __builtin_amdgcn_exp2f(x);
#else
    return exp2f(x);
#endif
}

// Key-position permutation: actual key s (within a 32-key group, s = 8q+4t+j)
// -> LDS/position index p = 16t + 4q + j. Makes the S^T output of two 16-key
// tiles land exactly in the A-fragment layout of mfma_f32_16x16x32_bf16
// (A[m=l16][k=8*quad+j] over actual keys), so PV needs no cross-lane exchange.
__device__ __forceinline__ int prem(int s) {
    return (s & ~31) | ((s & 4) << 2) | ((s >> 1) & 12) | (s & 3);
}

#define GLD16(gp, lp) __builtin_amdgcn_global_load_lds( \
    (const __attribute__((address_space(1))) void*)(gp), \
    (__attribute__((address_space(3))) void*)(lp), 16, 0, 0)

// ---------------- fp32 W[K][N] -> bf16 Wt[N][K], all three weights in one launch ----------------
// r16: vectorized global access — fv4 16B loads (4 iters vs 16) and sh4 8B
// stores (values/order bit-identical). LDS t[64][65] stores stay scalar (odd
// stride 65 spreads banks; an fv4 LDS store would be unaligned for odd rows).
__global__ __launch_bounds__(256) void cvt_wT3(const float* __restrict__ W0, const float* __restrict__ W1,
                                               const float* __restrict__ W2, u16* __restrict__ Wt) {
    __shared__ float t[64][65];
    const float* Wsrc = blockIdx.z == 0 ? W0 : (blockIdx.z == 1 ? W1 : W2);
    u16* dst = Wt + (size_t)blockIdx.z * DM * DM;
    int r0 = blockIdx.x * 64, c0 = blockIdx.y * 64;
    #pragma unroll
    for (int i = 0; i < 4; ++i) {
        int idx = i * 256 + threadIdx.x;
        int r = idx >> 4, c4 = (idx & 15) * 4;
        fv4 v = *(const fv4*)&Wsrc[(size_t)(r0 + r) * DM + c0 + c4];
        #pragma unroll
        for (int j = 0; j < 4; ++j) t[r][c4 + j] = v[j];
    }
    __syncthreads();
    #pragma unroll
    for (int i = 0; i < 4; ++i) {
        int idx = i * 256 + threadIdx.x;
        int n = idx >> 4, k4 = (idx & 15) * 4;
        sh4 pk;
        #pragma unroll
        for (int j = 0; j < 4; ++j) pk[j] = (short)f2bf(t[k4 + j][n]);
        *(sh4*)&dst[(size_t)(c0 + n) * DM + r0 + k4] = pk;
    }
}

// ---------------- fused projection GEMMs: z in {Q,K,V}, [8192,1024]x[1024,1024]+bias ----------------
// ROUND-5 main loop (best of 5 measured variants). A fp32 -> regs -> cvt_pk ->
// swizzled LDS; B via GLD16 double-buffered; counted vmcnt(12).
// r12: LDS-staged coalesced epilogue (WRITE 71->48MB). r13: chunk XOR-swizzle
// on the staging tile (bank conflicts 4.46M->262K, -5us). r14: mk_mbias folded
// in (neutral; kept — one fewer launch).
// z=0: Q -> [b][h][s][d];  z=1: K -> [b][h][prem(s)][d];  z=2: V -> [b][h][d][s]
__global__ __launch_bounds__(256, 3) void gemm3(const float* __restrict__ Qf, const float* __restrict__ Kf,
                                                const float* __restrict__ Vf, const u16* __restrict__ Wt3,
                                                const float* __restrict__ bq, const float* __restrict__ bk,
                                                const float* __restrict__ bv, u16* __restrict__ out3,
                                                const int* __restrict__ mask, float* __restrict__ mb) {
    __shared__ u16 As[128 * 64];
    __shared__ u16 Bs[2][128 * 64];
    int z = blockIdx.z;
    const float* Af = z == 0 ? Qf : (z == 1 ? Kf : Vf);
    const float* bias = z == 0 ? bq : (z == 1 ? bk : bv);
    int vmode = z == 0 ? 0 : (z == 1 ? 2 : 1);
    const u16* Bg = Wt3 + (size_t)z * DM * DM + (size_t)blockIdx.y * 128 * DM;
    u16* outp = out3 + (size_t)z * 8388608u;   // 8192*1024 u16 per projection

    int tid = threadIdx.x;
    int w = tid >> 6, lane = tid & 63, quad = lane >> 4, l16 = lane & 15;
    int wm = w >> 1, wn = w & 1;
    int r8 = lane >> 3, cg = (lane & 7) ^ r8;

    int arow0 = w * 32 + (lane >> 4);
    int acol = (lane & 15) * 4;
    const float* Ag = Af + (size_t)(blockIdx.x * 128 + arow0) * DM + acol;
    int ach = (lane & 15) >> 1, asub = lane & 1;

    // fused mask-bias (issued before the pipeline loads so the implicit A(0)
    // wait drains it)
    if (z == 2 && blockIdx.y == 0 && blockIdx.x < 32) {
        int i = blockIdx.x * 256 + tid;
        mb[prem(i)] = mask[i] ? -M2BIAS : -__builtin_inff();
    }

    f4 acc[4][4];
    #pragma unroll
    for (int mt = 0; mt < 4; ++mt)
        #pragma unroll
        for (int nt = 0; nt < 4; ++nt) acc[mt][nt] = f4{0.f, 0.f, 0.f, 0.f};

    fv4 ar[8];
    auto loadA = [&](int kt) {
        const float* src = Ag + kt * 64;
        #pragma unroll
        for (int j = 0; j < 8; ++j) ar[j] = *(const fv4*)(src + (size_t)j * 4 * DM);
    };
    auto stageB = [&](int buf, int kt) {
        int kofs = kt * 64 + cg * 8;
        #pragma unroll
        for (int c = 0; c < 4; ++c) {
            int rbase = w * 32 + c * 8;
            GLD16(Bg + (size_t)(rbase + r8) * DM + kofs, &Bs[buf][rbase * 64]);
        }
    };

    stageB(0, 0);
    loadA(0);

    for (int kt = 0; kt < 16; ++kt) {
        // prefetch next B tile into the other LDS buffer (stays in flight
        // across the barrier; covered by this iteration's MFMA phase)
        if (kt + 1 < 16) stageB((kt + 1) & 1, kt + 1);
        // convert current A regs -> swizzled LDS (implicit vmcnt here waits for
        // A(kt) and thereby also drains the older B(kt) GLD16s)
        #pragma unroll
        for (int j = 0; j < 8; ++j) {
            unsigned lo, hi;
            asm("v_cvt_pk_bf16_f32 %0, %1, %2" : "=v"(lo) : "v"(ar[j][0]), "v"(ar[j][1]));
            asm("v_cvt_pk_bf16_f32 %0, %1, %2" : "=v"(hi) : "v"(ar[j][2]), "v"(ar[j][3]));
            int row = arow0 + j * 4;
            uint2 pk; pk.x = lo; pk.y = hi;
            *(uint2*)&As[row * 64 + (ach ^ (row & 7)) * 8 + asub * 4] = pk;
        }
        // prefetch next A tile into the SAME regs (WAR: after converts read them)
        if (kt + 1 < 16) loadA(kt + 1);

        // pre-MFMA barrier: drain ds_writes + anything older than this
        // iteration's 12 prefetch loads; do NOT drain the prefetches.
        if (kt < 15) {
            asm volatile("s_waitcnt vmcnt(12) lgkmcnt(0)" ::: "memory");
        } else {
            asm volatile("s_waitcnt vmcnt(0) lgkmcnt(0)" ::: "memory");
        }
        __builtin_amdgcn_s_barrier();
        asm volatile("" ::: "memory");

        #pragma unroll
        for (int ks = 0; ks < 2; ++ks) {
            bf16x8 afr[4], bfr[4];
            #pragma unroll
            for (int mt = 0; mt < 4; ++mt) {
                int row = wm * 64 + mt * 16 + l16;
                int ch = (ks * 4 + quad) ^ (row & 7);
                afr[mt] = *(const bf16x8*)&As[row * 64 + ch * 8];
            }
            #pragma unroll
            for (int nt = 0; nt < 4; ++nt) {
                int row = wn * 64 + nt * 16 + l16;
                int ch = (ks * 4 + quad) ^ (row & 7);
                bfr[nt] = *(const bf16x8*)&Bs[kt & 1][row * 64 + ch * 8];
            }
            #pragma unroll
            for (int mt = 0; mt < 4; ++mt)
                #pragma unroll
                for (int nt = 0; nt < 4; ++nt)
                    acc[mt][nt] = __builtin_amdgcn_mfma_f32_16x16x32_bf16(afr[mt], bfr[nt], acc[mt][nt], 0, 0, 0);
        }
        // post-MFMA barrier: all waves' LDS reads done before next iteration's
        // As/Bs writes.
        asm volatile("" ::: "memory");
        __builtin_amdgcn_s_barrier();
        asm volatile("" ::: "memory");
    }

    // ---- epilogue: stage C-tile (bias-added bf16) in LDS, then 16B coalesced stores ----
    // Swizzled tile: (row,col) -> row*128 + ((col>>3) ^ ((row>>1)&7))*8 + (col&7).
    u16* tile = &Bs[0][0];   // 128 x 128 u16 = 32 KB exactly
    #pragma unroll
    for (int nt = 0; nt < 4; ++nt) {
        int cl = wn * 64 + nt * 16 + l16;                 // local ncol
        float bn = bias[blockIdx.y * 128 + cl];
        #pragma unroll
        for (int mt = 0; mt < 4; ++mt) {
            int sl = wm * 64 + mt * 16 + quad * 4;        // local s (base of 4)
            #pragma unroll
            for (int reg = 0; reg < 4; ++reg) {
                u16 v = f2bf(acc[mt][nt][reg] + bn);
                if (vmode == 1) {
                    int row = cl, col = sl + reg;         // [ncol][s]
                    tile[row * 128 + (((col >> 3) ^ ((row >> 1) & 7)) << 3) + (col & 7)] = v;
                } else {
                    int row = sl + reg, col = cl;         // [s][ncol]
                    tile[row * 128 + (((col >> 3) ^ ((row >> 1) & 7)) << 3) + (col & 7)] = v;
                }
            }
        }
    }
    __syncthreads();
    int sbase = blockIdx.x * 128;
    int bidx = sbase >> 11, s0b = sbase & 2047;
    #pragma unroll
    for (int i = 0; i < 8; ++i) {
        int chunk = i * 256 + tid;            // 2048 chunks of 8 u16 (16B)
        int row = chunk >> 4, cc = chunk & 15;
        bf16x8 val = *(const bf16x8*)&tile[row * 128 + ((cc ^ ((row >> 1) & 7)) << 3)];
        size_t gidx;
        if (vmode == 1) {
            // out[b][h][d][s]: tile row = local ncol, 8 consecutive s
            int ncol = blockIdx.y * 128 + row;
            gidx = (((size_t)bidx * NH + (ncol >> 6)) * 64 + (ncol & 63)) * SQ + s0b + cc * 8;
        } else {
            // out[b][h][s][d]: tile row = local s, 8 consecutive d (within one h)
            int s = s0b + row;
            int sg = (vmode == 2) ? prem(s) : s;
            int ncol0 = blockIdx.y * 128 + cc * 8;
            gidx = (((size_t)bidx * NH + (ncol0 >> 6)) * SQ + sg) * 64 + (ncol0 & 63);
        }
        *(bf16x8*)&outp[gidx] = val;
    }
}

// ---------------- flash attention (S^T form, register-resident P, K=32 PV) ----------------
// Round-2 structure (98.2us) + r15 mask-bias-in-LDS (-12us). r17: V-fragment
// ds_reads (bv8, both 32-key groups) hoisted ABOVE the QK^T MFMA cluster —
// they depend only on `buf` (valid from the iteration-top syncthreads), and
// issuing them before 16 MFMAs + softmax gives the LDS reads ~600 cycles of
// cover instead of sitting directly before their PV consumers. Same reads,
// same values; VGPR +32 (~96 < 128 cap at 4 waves/EU) — no spill possible.
__global__ __launch_bounds__(256, 4) void attn(const u16* __restrict__ qw, const u16* __restrict__ kw,
                                               const u16* __restrict__ vtw, const float* __restrict__ mbias,
                                               float* __restrict__ outp) {
    __shared__ u16 Ks[2][64 * 64];   // [key-position][64 d], 16B-chunk XOR swizzled
    __shared__ u16 Vs[2][64 * 64];   // [d][64 keys], 16B-chunk XOR swizzled
    __shared__ float mbL[SQ];        // 8 KB: whole mask-bias row for this batch
    int tid = threadIdx.x;
    int w = tid >> 6, lane = tid & 63, quad = lane >> 4, l16 = lane & 15;
    int r8 = lane >> 3, sl = lane & 7;
    int bh = blockIdx.x, b = bh >> 4;   // grid.x = bh for XCD L2 locality
    int h = bh & 15;
    int qbase = blockIdx.y * 128 + w * 32;
    const u16* qp = qw + (size_t)bh * SQ * 64;
    const u16* kp = kw + (size_t)bh * SQ * 64;
    const u16* vp = vtw + (size_t)bh * 64 * SQ;
    const float* mbp = mbias + b * SQ;

    // stage mask-bias row into LDS (coalesced; ordered by the kb=0 syncthreads)
    #pragma unroll
    for (int i = 0; i < 2; ++i) {
        int idx = (i * 256 + tid) * 4;
        *(fv4*)&mbL[idx] = *(const fv4*)&mbp[idx];
    }

    bf16x8 aq[2][2];  // Q frags (B-operand of S^T)
    #pragma unroll
    for (int mt = 0; mt < 2; ++mt)
        #pragma unroll
        for (int ks = 0; ks < 2; ++ks)
            aq[mt][ks] = *(const bf16x8*)&qp[(size_t)(qbase + mt * 16 + l16) * 64 + ks * 32 + quad * 8];

    f4 o[2][4];
    float lrow[2] = {0.f, 0.f};  // per-lane partial row-sum for q-row l16
    #pragma unroll
    for (int mt = 0; mt < 2; ++mt)
        #pragma unroll
        for (int nt = 0; nt < 4; ++nt) o[mt][nt] = f4{0.f, 0.f, 0.f, 0.f};

    auto stage = [&](int buf, int k0) {
        #pragma unroll
        for (int j = 0; j < 2; ++j) {
            int row = w * 16 + j * 8 + r8;
            int gsl = sl ^ (row & 7);
            GLD16(kp + (size_t)(k0 + row) * 64 + gsl * 8, &Ks[buf][(w * 16 + j * 8) * 64]);
            GLD16(vp + (size_t)row * SQ + k0 + gsl * 8, &Vs[buf][(w * 16 + j * 8) * 64]);
        }
    };

    stage(0, 0);
    for (int kb = 0; kb < 32; ++kb) {
        int buf = kb & 1;
        int k0 = kb * 64;
        __syncthreads();  // staging of `buf` done; all waves done reading buf^1
        if (kb + 1 < 32) stage(buf ^ 1, k0 + 64);

        // mask-bias from LDS (quad-uniform -> broadcast, conflict-free)
        fv4 bias4[4];
        #pragma unroll
        for (int kt = 0; kt < 4; ++kt)
            bias4[kt] = *(const fv4*)&mbL[k0 + kt * 16 + quad * 4];

        // K frags (A-operand of S^T)
        bf16x8 bk[4][2];
        #pragma unroll
        for (int kt = 0; kt < 4; ++kt)
            #pragma unroll
            for (int ks = 0; ks < 2; ++ks) {
                int r = kt * 16 + l16;
                int slot = (ks * 4 + quad) ^ (r & 7);
                bk[kt][ks] = *(const bf16x8*)&Ks[buf][r * 64 + slot * 8];
            }
        // V frags for BOTH 32-key groups, issued early: QK^T + softmax below
        // cover their LDS latency (r17 hoist).
        bf16x8 bv8[2][4];
        #pragma unroll
        for (int g = 0; g < 2; ++g)
            #pragma unroll
            for (int nt = 0; nt < 4; ++nt) {
                int row = nt * 16 + l16;  // d
                int ch = (g * 4 + quad) ^ (row & 7);
                bv8[g][nt] = *(const bf16x8*)&Vs[buf][row * 64 + ch * 8];
            }
        // S^T[kt][mt]: lane(quad,l16) regs = key-positions 16kt+4quad+r, q-row = l16
        f4 S[4][2];
        #pragma unroll
        for (int kt = 0; kt < 4; ++kt)
            #pragma unroll
            for (int mt = 0; mt < 2; ++mt) {
                f4 s = f4{0.f, 0.f, 0.f, 0.f};
                s = __builtin_amdgcn_mfma_f32_16x16x32_bf16(bk[kt][0], aq[mt][0], s, 0, 0, 0);
                s = __builtin_amdgcn_mfma_f32_16x16x32_bf16(bk[kt][1], aq[mt][1], s, 0, 0, 0);
                S[kt][mt] = s;
            }
        // softmax numerator + IMMEDIATE bf16 pack: per 32-key group g, the tile
        // pair (2g,2g+1) becomes one A-fragment pa8[g][mt] (keys g*32+8q+0..7).
        bf16x8 pa8[2][2];
        #pragma unroll
        for (int g = 0; g < 2; ++g)
            #pragma unroll
            for (int mt = 0; mt < 2; ++mt) {
                f4 se = S[2 * g][mt], so = S[2 * g + 1][mt];
                float p0 = fast_exp2(se[0] * SCALE2 + bias4[2 * g][0]);
                float p1 = fast_exp2(se[1] * SCALE2 + bias4[2 * g][1]);
                float p2 = fast_exp2(se[2] * SCALE2 + bias4[2 * g][2]);
                float p3 = fast_exp2(se[3] * SCALE2 + bias4[2 * g][3]);
                float q0 = fast_exp2(so[0] * SCALE2 + bias4[2 * g + 1][0]);
                float q1 = fast_exp2(so[1] * SCALE2 + bias4[2 * g + 1][1]);
                float q2 = fast_exp2(so[2] * SCALE2 + bias4[2 * g + 1][2]);
                float q3 = fast_exp2(so[3] * SCALE2 + bias4[2 * g + 1][3]);
                lrow[mt] += ((p0 + p1) + (p2 + p3)) + ((q0 + q1) + (q2 + q3));
                uv4 wv;
                wv[0] = (__float_as_uint(p1) & 0xFFFF0000u) | (__float_as_uint(p0) >> 16);
                wv[1] = (__float_as_uint(p3) & 0xFFFF0000u) | (__float_as_uint(p2) >> 16);
                wv[2] = (__float_as_uint(q1) & 0xFFFF0000u) | (__float_as_uint(q0) >> 16);
                wv[3] = (__float_as_uint(q3) & 0xFFFF0000u) | (__float_as_uint(q2) >> 16);
                pa8[g][mt] = __builtin_bit_cast(bf16x8, wv);
            }
        // PV at K=32: B = V^T b128 fragments (already in registers).
        #pragma unroll
        for (int g = 0; g < 2; ++g)
            #pragma unroll
            for (int mt = 0; mt < 2; ++mt)
                #pragma unroll
                for (int nt = 0; nt < 4; ++nt)
                    o[mt][nt] = __builtin_amdgcn_mfma_f32_16x16x32_bf16(pa8[g][mt], bv8[g][nt], o[mt][nt], 0, 0, 0);
    }

    // row sums: each q-row l16's partials live in the 4 quads; reduce, redistribute
    #pragma unroll
    for (int mt = 0; mt < 2; ++mt) {
        float v = lrow[mt];
        v += __shfl_xor(v, 16);
        v += __shfl_xor(v, 32);
        #pragma unroll
        for (int reg = 0; reg < 4; ++reg) {
            float inv = 1.f / __shfl(v, quad * 4 + reg);
            int row = qbase + mt * 16 + quad * 4 + reg;
            size_t obase = ((size_t)b * SQ + row) * DM + h * 64;
            #pragma unroll
            for (int nt = 0; nt < 4; ++nt)
                outp[obase + nt * 16 + l16] = o[mt][nt][reg] * inv;
        }
    }
}

extern "C" void kernel_launch(void* const* d_in, const int* in_sizes, int n_in,
                              void* d_out, int out_size, void* d_ws, size_t ws_size,
                              hipStream_t stream) {
    (void)in_sizes; (void)n_in; (void)out_size; (void)ws_size;
    const float* Q  = (const float*)d_in[0];
    const float* K  = (const float*)d_in[1];
    const float* V  = (const float*)d_in[2];
    const int* mask = (const int*)d_in[3];
    const float* Wq = (const float*)d_in[4];
    const float* bq = (const float*)d_in[5];
    const float* Wk = (const float*)d_in[6];
    const float* bk = (const float*)d_in[7];
    const float* Wv = (const float*)d_in[8];
    const float* bv = (const float*)d_in[9];
    float* out = (float*)d_out;
    char* ws = (char*)d_ws;
    u16* q_ws  = (u16*)(ws);                                  // 16 MB  [b][h][s][d]
    u16* k_ws  = (u16*)(ws + (size_t)16 * 1024 * 1024);       // 16 MB  [b][h][prem(s)][d]
    u16* v_ws  = (u16*)(ws + (size_t)32 * 1024 * 1024);       // 16 MB  [b][h][d][s]
    u16* wbuf3 = (u16*)(ws + (size_t)48 * 1024 * 1024);       //  6 MB  [3][N][K] bf16
    float* mb  = (float*)(ws + (size_t)54 * 1024 * 1024);     // 32 KB

    cvt_wT3<<<dim3(16, 16, 3), 256, 0, stream>>>(Wq, Wk, Wv, wbuf3);
    gemm3<<<dim3(64, 8, 3), 256, 0, stream>>>(Q, K, V, wbuf3, bq, bk, bv, q_ws, mask, mb);
    attn<<<dim3(64, 16), 256, 0, stream>>>(q_ws, k_ws, v_ws, mb, out);
}